// Round 9
// baseline (132.872 us; speedup 1.0000x reference)
//
#include <hip/hip_runtime.h>
#include <cmath>

#define NS 88
#define NL 10
#define NT 30
#define NE 768
#define NH 64
#define NG 256   // 4*H
#define NM 300   // L*T

typedef _Float16 half_t;
typedef __attribute__((ext_vector_type(2))) _Float16 half2_t;
typedef __attribute__((ext_vector_type(8))) _Float16 half8;
typedef __attribute__((ext_vector_type(4))) _Float16 half4v;
typedef __attribute__((ext_vector_type(4))) float f32x4;

__device__ inline void gload_lds16(const void* g, void* l) {
  __builtin_amdgcn_global_load_lds(
      (const __attribute__((address_space(1))) unsigned int*)g,
      (__attribute__((address_space(3))) unsigned int*)l, 16, 0, 0);
}

#define WAITV(N) asm volatile("s_waitcnt vmcnt(" #N ")" ::: "memory")
#define LGKM0    asm volatile("s_waitcnt lgkmcnt(0)" ::: "memory")

// fast sigmoid/tanh: v_exp_f32 + v_rcp_f32
__device__ inline float fsigmoid(float x) {
  return __builtin_amdgcn_rcpf(1.f + __expf(-x));
}
__device__ inline float ftanh(float x) {
  float e = __expf(2.f * x);
  return 1.f - 2.f * __builtin_amdgcn_rcpf(e + 1.f);
}

#if __has_builtin(__builtin_amdgcn_fdot2)
__device__ inline float fdot2(half2_t a, half2_t b, float c) {
  return __builtin_amdgcn_fdot2(a, b, c, false);   // v_dot2_f32_f16
}
#else
__device__ inline float fdot2(half2_t a, half2_t b, float c) {
  return fmaf((float)a[1], (float)b[1], fmaf((float)a[0], (float)b[0], c));
}
#endif

__device__ inline half2_t mk_h2(float a, float b) {
  half2_t r; r[0] = (half_t)a; r[1] = (half_t)b; return r;
}

// ---------------------------------------------------------------------------
// convB: Uall_w fp32 [S,768,256] -> fp16 transposed [S,256,768] (n-major,
// k contiguous). LDS 32x32 tile transpose. Grid: S * 24 * 8 blocks.
// ---------------------------------------------------------------------------
__global__ __launch_bounds__(256) void convB_kernel(
    const float* __restrict__ in, half_t* __restrict__ out)
{
  __shared__ float tile[32][36];
  int b  = blockIdx.x;
  int s  = b / 192;
  int r  = b % 192;
  int kt = r / 8;
  int nt = r % 8;
  int t  = threadIdx.x;

  int kk  = t >> 3;
  int nn4 = (t & 7) * 4;
  float4 v = *(const float4*)(in + ((size_t)s * NE + kt * 32 + kk) * NG + nt * 32 + nn4);
  tile[kk][nn4 + 0] = v.x; tile[kk][nn4 + 1] = v.y;
  tile[kk][nn4 + 2] = v.z; tile[kk][nn4 + 3] = v.w;
  __syncthreads();

  int nn = t >> 3;
  int kq = (t & 7) * 4;
  half4v o;
#pragma unroll
  for (int j = 0; j < 4; ++j) o[j] = (half_t)tile[kq + j][nn];
  *(half4v*)(out + ((size_t)s * NG + nt * 32 + nn) * NE + kt * 32 + kq) = o;
}

// ---------------------------------------------------------------------------
// gemm_mfma: U[s,m,n] = text[s,m,:] . Bf16[s,n,:] + bias[s,n]
// 128m x 128n tile, BK=32, 24 K-steps, 528 blocks (88 x 3m x 2n), 256 thr
// (4 waves, 2m x 2n). TRIPLE-buffered LDS (3 x 16KB), prefetch distance 2,
// counted s_waitcnt vmcnt(6) (never 0 in steady state), raw s_barrier —
// one barrier per step. A reg-staged f32->f16 with XOR-swizzled ds_write
// (chunk c at slot c^(row&3)); B via global_load_lds with inverse-swizzled
// per-lane source (same involution). 6 vmem ops/thread/stage.
// ---------------------------------------------------------------------------
__global__ __launch_bounds__(256) void gemm_mfma_kernel(
    const float*  __restrict__ text,  // [S,300,768] f32
    const half_t* __restrict__ Bf16,  // [S,256,768] f16 (n-major, k contig)
    const float*  __restrict__ bias,  // [S,256]
    float* __restrict__ U)            // [S,300,256]
{
  __shared__ uint4 smem4[3072];       // 48 KiB: buf i at i*16KB (A 8K, B 8K)
  char* smem = (char*)smem4;

  int b   = blockIdx.x;
  int swz = (b & 7) * 66 + (b >> 3);  // 528 = 8*66, bijective XCD swizzle
  int s   = swz / 6;
  int r   = swz % 6;
  int m0  = (r >> 1) * 128;           // 0,128,256 (rows 300..383 zeroed)
  int n0  = (r & 1) * 128;

  int tid = threadIdx.x;
  int w = tid >> 6, l = tid & 63;
  int wm = w >> 1, wn = w & 1;        // 2m x 2n wave grid (64x64 each)
  int lr = l & 15, lk = l >> 4;       // fragment row, k-group

  const float*  At = text + (size_t)s * NM * NE;
  const half_t* Bb = Bf16 + ((size_t)s * NG + n0) * NE;

  f32x4 acc[4][4];
#pragma unroll
  for (int i = 0; i < 4; ++i)
#pragma unroll
    for (int j = 0; j < 4; ++j) acc[i][j] = (f32x4){0.f, 0.f, 0.f, 0.f};

  float4 ra0[2][2], ra1[2][2];        // two named A-stage register sets

  // stage(K): 4 A f32 loads -> RA, 2 B gload_lds -> buf[K%3]. 6 vmem ops.
#define STAGE_ISSUE(K, RA)                                                   \
  {                                                                          \
    int kOff = (K) * 32;                                                     \
    _Pragma("unroll")                                                        \
    for (int j = 0; j < 2; ++j) {                                            \
      int idx = j * 256 + tid;                                               \
      int row = idx >> 2;                                                    \
      int m   = m0 + row;                                                    \
      const float* p = At + (size_t)(m < NM ? m : NM - 1) * NE + kOff +      \
                       (idx & 3) * 8;                                        \
      RA[j][0] = *(const float4*)p;                                          \
      RA[j][1] = *(const float4*)(p + 4);                                    \
    }                                                                        \
    char* Bdst = smem + ((K) % 3) * 16384 + 8192;                            \
    _Pragma("unroll")                                                        \
    for (int j = 0; j < 2; ++j) {                                            \
      int ci  = j * 256 + tid;                                               \
      int row = ci >> 2;                                                     \
      int c   = (ci & 3) ^ (row & 3);                                        \
      gload_lds16(Bb + (size_t)row * NE + (K) * 32 + c * 8,                  \
                  Bdst + j * 4096 + w * 1024);                               \
    }                                                                        \
  }

#define STAGE_WRITE_A(K, RA)                                                 \
  {                                                                          \
    char* Adst = smem + ((K) % 3) * 16384;                                   \
    _Pragma("unroll")                                                        \
    for (int j = 0; j < 2; ++j) {                                            \
      int idx = j * 256 + tid;                                               \
      int row = idx >> 2, c = idx & 3;                                       \
      int m   = m0 + row;                                                    \
      half8 av;                                                              \
      av[0] = (half_t)RA[j][0].x; av[1] = (half_t)RA[j][0].y;                \
      av[2] = (half_t)RA[j][0].z; av[3] = (half_t)RA[j][0].w;                \
      av[4] = (half_t)RA[j][1].x; av[5] = (half_t)RA[j][1].y;                \
      av[6] = (half_t)RA[j][1].z; av[7] = (half_t)RA[j][1].w;                \
      if (m >= NM) {                                                         \
        _Pragma("unroll")                                                    \
        for (int q = 0; q < 8; ++q) av[q] = (half_t)0.f;                     \
      }                                                                      \
      *(half8*)(Adst + row * 64 + ((c ^ (row & 3)) * 16)) = av;              \
    }                                                                        \
  }

#define COMPUTE(K)                                                           \
  {                                                                          \
    char* Abuf = smem + ((K) % 3) * 16384;                                   \
    char* Bbuf = Abuf + 8192;                                                \
    half8 af[4], bf[4];                                                      \
    _Pragma("unroll")                                                        \
    for (int fm = 0; fm < 4; ++fm) {                                         \
      int rw = wm * 64 + fm * 16 + lr;                                       \
      af[fm] = *(const half8*)(Abuf + rw * 64 + ((lk ^ (rw & 3)) * 16));     \
    }                                                                        \
    _Pragma("unroll")                                                        \
    for (int fn = 0; fn < 4; ++fn) {                                         \
      int rw = wn * 64 + fn * 16 + lr;                                       \
      bf[fn] = *(const half8*)(Bbuf + rw * 64 + ((lk ^ (rw & 3)) * 16));     \
    }                                                                        \
    _Pragma("unroll")                                                        \
    for (int fm = 0; fm < 4; ++fm)                                           \
      _Pragma("unroll")                                                      \
      for (int fn = 0; fn < 4; ++fn)                                         \
        acc[fm][fn] = __builtin_amdgcn_mfma_f32_16x16x32_f16(                \
            af[fm], bf[fn], acc[fm][fn], 0, 0, 0);                           \
  }

  // prologue: stage 0 and 1 (12 vmem in flight), write A(0), publish buf0
  STAGE_ISSUE(0, ra0);
  STAGE_ISSUE(1, ra1);
  WAITV(8);                 // A(0) loads complete (compiler also tracks regs)
  STAGE_WRITE_A(0, ra0);
  LGKM0;
  __builtin_amdgcn_s_barrier();

  // main loop: iter k = [issue(k+2) | vmcnt(6) | writeA(k+1) | compute(k)
  //                      | lgkm0 + barrier]. Unrolled in pairs for static
  //                      ra0/ra1 naming (rule #20).
#pragma unroll 1
  for (int kb = 0; kb < 24; kb += 2) {
    // even step: issues into ra0, writes A from ra1
    if (kb + 2 < 24) STAGE_ISSUE(kb + 2, ra0);
    if (kb + 2 < 24) { WAITV(6); } else { WAITV(0); }
    if (kb + 1 < 24) STAGE_WRITE_A(kb + 1, ra1);
    COMPUTE(kb);
    LGKM0;
    __builtin_amdgcn_s_barrier();

    // odd step: issues into ra1, writes A from ra0
    int k1 = kb + 1;
    if (k1 + 2 < 24) STAGE_ISSUE(k1 + 2, ra1);
    if (k1 + 2 < 24) { WAITV(6); } else { WAITV(0); }
    if (k1 + 1 < 24) STAGE_WRITE_A(k1 + 1, ra0);
    COMPUTE(k1);
    if (k1 < 23) {
      LGKM0;
      __builtin_amdgcn_s_barrier();
    }
  }
#undef STAGE_ISSUE
#undef STAGE_WRITE_A
#undef COMPUTE

  // epilogue: D row = lk*4+e, col = lr (m89 layout); add bias, f32 store
#pragma unroll
  for (int fn = 0; fn < 4; ++fn) {
    int col = n0 + wn * 64 + fn * 16 + lr;
    float bv = bias[(size_t)s * NG + col];
#pragma unroll
    for (int fm = 0; fm < 4; ++fm) {
      int mbase = m0 + wm * 64 + fm * 16 + lk * 4;
#pragma unroll
      for (int e = 0; e < 4; ++e) {
        int m = mbase + e;
        if (m < NM)
          U[((size_t)s * NM + m) * NG + col] = acc[fm][fn][e] + bv;
      }
    }
  }
}

// ---------------------------------------------------------------------------
// TimeLSTM + text attention FUSED. One wave per (stock, day) — barrier-free.
// ---------------------------------------------------------------------------
__global__ __launch_bounds__(64) void lstm_attn_kernel(
    const float* __restrict__ u,       // [S, L*T, 256] f32
    const float* __restrict__ time_in, // [S, L, T]
    const float* __restrict__ Wdw,  const float* __restrict__ Wdb,
    const float* __restrict__ Wallw, const float* __restrict__ Wallb,
    const float* __restrict__ tW1w, const float* __restrict__ tW1b,
    const float* __restrict__ tW2w, const float* __restrict__ tW2b,
    const float* __restrict__ tVw,  const float* __restrict__ tVb,
    float* __restrict__ day_vec)       // [S, L, H]
{
  int bid = blockIdx.x;                // s*NL + l
  int s = bid / NL;
  int j = threadIdx.x;                 // 0..63

  __shared__ float   u_s[NT * NG];     // 30 KiB
  __shared__ float   hist[NT][NH];     // 7.5 KiB
  __shared__ float   ts_s[NT];
  __shared__ half2_t h2_s[NH / 2];
  __shared__ half2_t c2_s[NH / 2];

  // stage u tile: 30 rows x 1KB, per-lane source (lane j -> bytes 16j..16j+16)
  const float* u_base = u + (size_t)bid * NT * NG;
#pragma unroll
  for (int i = 0; i < NT; ++i)
    gload_lds16(u_base + i * NG + j * 4, (char*)u_s + i * 1024);

  if (j < NT) ts_s[j] = time_in[(size_t)bid * NT + j];
  ((half_t*)h2_s)[j] = (half_t)0.f;
  ((half_t*)c2_s)[j] = (half_t)0.f;

  // weights -> packed f16 pairs in VGPRs
  const float* Wa  = Wallw + (size_t)s * NH * NG;
  const float* Wdp = Wdw   + (size_t)s * NH * NH;
  half2_t wf[32], wi[32], wo[32], wg[32], wd[32];
#pragma unroll
  for (int k2 = 0; k2 < 32; ++k2) {
    wf[k2] = mk_h2(Wa[(2*k2) * NG + j],        Wa[(2*k2+1) * NG + j]);
    wi[k2] = mk_h2(Wa[(2*k2) * NG + 64 + j],   Wa[(2*k2+1) * NG + 64 + j]);
    wo[k2] = mk_h2(Wa[(2*k2) * NG + 128 + j],  Wa[(2*k2+1) * NG + 128 + j]);
    wg[k2] = mk_h2(Wa[(2*k2) * NG + 192 + j],  Wa[(2*k2+1) * NG + 192 + j]);
    wd[k2] = mk_h2(Wdp[(2*k2) * NH + j],       Wdp[(2*k2+1) * NH + j]);
  }
  float bf = Wallb[(size_t)s * NG + j];
  float bi = Wallb[(size_t)s * NG + 64 + j];
  float bo = Wallb[(size_t)s * NG + 128 + j];
  float bg = Wallb[(size_t)s * NG + 192 + j];
  float bd = Wdb[(size_t)s * NH + j];

  // drain global_load_lds before reading u_s (single wave: no barrier)
  asm volatile("s_waitcnt vmcnt(0)" ::: "memory");

  float c_my = 0.f;
  for (int t = 0; t < NT; ++t) {
    float accf = bf + u_s[t * NG + j];
    float acci = bi + u_s[t * NG + 64 + j];
    float acco = bo + u_s[t * NG + 128 + j];
    float accg = bg + u_s[t * NG + 192 + j];
    float accd = bd;
#pragma unroll
    for (int k2 = 0; k2 < 32; ++k2) {
      half2_t hv = h2_s[k2];
      half2_t cv = c2_s[k2];
      accf = fdot2(hv, wf[k2], accf);
      acci = fdot2(hv, wi[k2], acci);
      acco = fdot2(hv, wo[k2], acco);
      accg = fdot2(hv, wg[k2], accg);
      accd = fdot2(cv, wd[k2], accd);
    }
    float f  = fsigmoid(accf);          // reference: all-sigmoid gates
    float ii = fsigmoid(acci);
    float o  = fsigmoid(acco);
    float gg = fsigmoid(accg);
    float cadj = c_my + ftanh(accd) * (ts_s[t] - 1.f);
    float cn = fmaf(f, cadj, ii * gg);
    c_my = cn;
    float hn = o * ftanh(cn);
    ((half_t*)h2_s)[j] = (half_t)hn;
    ((half_t*)c2_s)[j] = (half_t)cn;
    hist[t][j] = hn;                    // keep history in LDS (f32)
  }

  // ---- text attention over T (same wave; hist complete, ds-ordered) ----
  const float* tW1p = tW1w + (size_t)s * NH * NH;
  const float* tW2p = tW2w + (size_t)s * NH * NH;

  float tw2c[NH];                       // tW2 column j in regs
#pragma unroll
  for (int h = 0; h < NH; ++h) tw2c[h] = tW2p[(size_t)h * NH + j];

  float a1 = tW1b[(size_t)s * NH + j];
  {
    const float4* h4 = (const float4*)&hist[NT - 1][0];
#pragma unroll
    for (int q = 0; q < NH / 4; ++q) {
      float4 v = h4[q];
      a1 = fmaf(v.x, tW1p[(size_t)(4*q+0) * NH + j], a1);
      a1 = fmaf(v.y, tW1p[(size_t)(4*q+1) * NH + j], a1);
      a1 = fmaf(v.z, tW1p[(size_t)(4*q+2) * NH + j], a1);
      a1 = fmaf(v.w, tW1p[(size_t)(4*q+3) * NH + j], a1);
    }
  }
  float b2k = tW2b[(size_t)s * NH + j];
  float tv  = tVw[(size_t)s * NH + j];
  float tvb = tVb[s];

  float sc[NT];
#pragma unroll
  for (int t = 0; t < NT; ++t) {
    float a2 = b2k;
    const float4* h4 = (const float4*)&hist[t][0];
#pragma unroll
    for (int q = 0; q < NH / 4; ++q) {
      float4 v = h4[q];
      a2 = fmaf(v.x, tw2c[4*q+0], a2);
      a2 = fmaf(v.y, tw2c[4*q+1], a2);
      a2 = fmaf(v.z, tw2c[4*q+2], a2);
      a2 = fmaf(v.w, tw2c[4*q+3], a2);
    }
    float v = ftanh(a1 + a2) * tv;
#pragma unroll
    for (int off = 32; off >= 1; off >>= 1) v += __shfl_xor(v, off);
    sc[t] = v + tvb;
  }
  float mx = sc[0];
#pragma unroll
  for (int t = 1; t < NT; ++t) mx = fmaxf(mx, sc[t]);
  float sum = 0.f;
#pragma unroll
  for (int t = 0; t < NT; ++t) { sc[t] = __expf(sc[t] - mx); sum += sc[t]; }
  float inv = __builtin_amdgcn_rcpf(sum);
  float dv = 0.f;
#pragma unroll
  for (int t = 0; t < NT; ++t) dv = fmaf(sc[t] * inv, hist[t][j], dv);
  day_vec[(size_t)bid * NH + j] = dv;
}

// ---------------------------------------------------------------------------
// day LSTM + day attention + pred head. One block per stock.
// ---------------------------------------------------------------------------
__global__ __launch_bounds__(256) void day_head_kernel(
    const float* __restrict__ day_vec, // [S, L, H]
    const float* __restrict__ ihw, const float* __restrict__ ihb,
    const float* __restrict__ hhb,
    const float* __restrict__ dW1w, const float* __restrict__ dW1b,
    const float* __restrict__ dW2w, const float* __restrict__ dW2b,
    const float* __restrict__ dVw,  const float* __restrict__ dVb,
    const float* __restrict__ predw, const float* __restrict__ predb,
    float* __restrict__ out)           // [S]
{
  int s = blockIdx.x;
  int g = threadIdx.x;
  int j = g & 63;
  int q = g >> 6;

  __shared__ float dv_s[NL][NH];
  __shared__ float gl[NL][NG];
  __shared__ float hd[NL][NH];

  for (int i = g; i < NL * NH; i += 256)
    ((float*)dv_s)[i] = day_vec[(size_t)s * NL * NH + i];
  __syncthreads();

  float ihcol[NH];
#pragma unroll
  for (int k = 0; k < NH; ++k)
    ihcol[k] = ihw[((size_t)s * NH + k) * NG + g];
  float bias = ihb[(size_t)s * NG + g] + hhb[(size_t)s * NG + g];

  bool is_gpart = (g >= 128 && g < 192);
  for (int l = 0; l < NL; ++l) {
    float acc = bias;
#pragma unroll
    for (int k = 0; k < NH; ++k) acc = fmaf(dv_s[l][k], ihcol[k], acc);
    gl[l][g] = is_gpart ? ftanh(acc) : fsigmoid(acc);
  }
  __syncthreads();
  for (int l = q; l < NL; l += 4) {
    float cd = gl[l][j] * gl[l][128 + j];       // sig(i)*tanh(g)
    hd[l][j] = gl[l][192 + j] * ftanh(cd);      // sig(o)*tanh(c)
  }
  __syncthreads();

  if (g < 64) {
    int k = g;
    float dw1c[NH], dw2c[NH];
#pragma unroll
    for (int h = 0; h < NH; ++h) {
      dw1c[h] = dW1w[((size_t)s * NH + h) * NH + k];
      dw2c[h] = dW2w[((size_t)s * NH + h) * NH + k];
    }
    float b1 = dW1b[(size_t)s * NH + k];
    float b2 = dW2b[(size_t)s * NH + k];
    float dv = dVw[(size_t)s * NH + k];
    float dvb = dVb[s];

    float sc[NL];
#pragma unroll
    for (int l = 0; l < NL; ++l) {
      float x1 = b1, x2 = b2;
#pragma unroll
      for (int h = 0; h < NH; ++h) {
        x1 = fmaf(hd[l][h], dw1c[h], x1);
        x2 = fmaf(hd[l][h], dw2c[h], x2);
      }
      float v = ftanh(x1 + x2) * dv;
#pragma unroll
      for (int off = 32; off >= 1; off >>= 1) v += __shfl_xor(v, off);
      sc[l] = v + dvb;
    }
    float mx = sc[0];
#pragma unroll
    for (int l = 1; l < NL; ++l) mx = fmaxf(mx, sc[l]);
    float sum = 0.f;
#pragma unroll
    for (int l = 0; l < NL; ++l) { sc[l] = __expf(sc[l] - mx); sum += sc[l]; }
    float inv = __builtin_amdgcn_rcpf(sum);
    float sv = 0.f;
#pragma unroll
    for (int l = 0; l < NL; ++l) sv = fmaf(sc[l] * inv, hd[l][k], sv);

    float p = sv * predw[k];
#pragma unroll
    for (int off = 32; off >= 1; off >>= 1) p += __shfl_xor(p, off);
    if (k == 0) {
      float x = p + predb[0];
      out[s] = (x >= 0.f) ? x : 0.01f * x;
    }
  }
}

// ---------------------------------------------------------------------------
extern "C" void kernel_launch(void* const* d_in, const int* in_sizes, int n_in,
                              void* d_out, int out_size, void* d_ws, size_t ws_size,
                              hipStream_t stream) {
  (void)in_sizes; (void)n_in; (void)out_size; (void)ws_size;

  const float* text    = (const float*)d_in[0];
  const float* time_in = (const float*)d_in[1];
  const float* Wdw     = (const float*)d_in[2];
  const float* Wdb     = (const float*)d_in[3];
  const float* Wallw   = (const float*)d_in[4];
  const float* Wallb   = (const float*)d_in[5];
  const float* Uallw   = (const float*)d_in[6];
  const float* Uallb   = (const float*)d_in[7];
  const float* tW1w    = (const float*)d_in[8];
  const float* tW1b    = (const float*)d_in[9];
  const float* tW2w    = (const float*)d_in[10];
  const float* tW2b    = (const float*)d_in[11];
  const float* tVw     = (const float*)d_in[12];
  const float* tVb     = (const float*)d_in[13];
  const float* ihw     = (const float*)d_in[14];
  const float* ihb     = (const float*)d_in[15];
  const float* hhb     = (const float*)d_in[16];
  const float* dW1w    = (const float*)d_in[17];
  const float* dW1b    = (const float*)d_in[18];
  const float* dW2w    = (const float*)d_in[19];
  const float* dW2b    = (const float*)d_in[20];
  const float* dVw     = (const float*)d_in[21];
  const float* dVb     = (const float*)d_in[22];
  const float* predw   = (const float*)d_in[23];
  const float* predb   = (const float*)d_in[24];

  float* ws      = (float*)d_ws;
  float* u       = ws;                                // S*300*256 f32
  float* day_vec = u + (size_t)NS * NM * NG;          // S*L*H    f32
  half_t* Bf16   = (half_t*)(day_vec + (size_t)NS * NL * NH); // S*256*768 f16

  convB_kernel<<<NS * 192, 256, 0, stream>>>(Uallw, Bf16);
  gemm_mfma_kernel<<<NS * 6, 256, 0, stream>>>(text, Bf16, Uallb, u);
  lstm_attn_kernel<<<NS * NL, 64, 0, stream>>>(u, time_in, Wdw, Wdb,
                                               Wallw, Wallb,
                                               tW1w, tW1b, tW2w, tW2b,
                                               tVw, tVb, day_vec);
  day_head_kernel<<<NS, 256, 0, stream>>>(day_vec, ihw, ihb, hhb,
                                          dW1w, dW1b, dW2w, dW2b, dVw, dVb,
                                          predw, predb, (float*)d_out);
}

// Round 10
// 131.729 us; speedup vs baseline: 1.0087x; 1.0087x over previous
//
#include <hip/hip_runtime.h>
#include <cmath>

#define NS 88
#define NL 10
#define NT 30
#define NE 768
#define NH 64
#define NG 256   // 4*H
#define NM 300   // L*T
#define NKS 2    // split-K slices

typedef _Float16 half_t;
typedef __attribute__((ext_vector_type(2))) _Float16 half2_t;
typedef __attribute__((ext_vector_type(8))) _Float16 half8;
typedef __attribute__((ext_vector_type(4))) _Float16 half4v;
typedef __attribute__((ext_vector_type(4))) float f32x4;

__device__ inline void gload_lds16(const void* g, void* l) {
  __builtin_amdgcn_global_load_lds(
      (const __attribute__((address_space(1))) unsigned int*)g,
      (__attribute__((address_space(3))) unsigned int*)l, 16, 0, 0);
}

// fast sigmoid/tanh: v_exp_f32 + v_rcp_f32
__device__ inline float fsigmoid(float x) {
  return __builtin_amdgcn_rcpf(1.f + __expf(-x));
}
__device__ inline float ftanh(float x) {
  float e = __expf(2.f * x);
  return 1.f - 2.f * __builtin_amdgcn_rcpf(e + 1.f);
}

#if __has_builtin(__builtin_amdgcn_fdot2)
__device__ inline float fdot2(half2_t a, half2_t b, float c) {
  return __builtin_amdgcn_fdot2(a, b, c, false);   // v_dot2_f32_f16
}
#else
__device__ inline float fdot2(half2_t a, half2_t b, float c) {
  return fmaf((float)a[1], (float)b[1], fmaf((float)a[0], (float)b[0], c));
}
#endif

__device__ inline half2_t mk_h2(float a, float b) {
  half2_t r; r[0] = (half_t)a; r[1] = (half_t)b; return r;
}

// ---------------------------------------------------------------------------
// convB: Uall_w fp32 [S,768,256] -> fp16 transposed [S,256,768] (n-major,
// k contiguous). LDS 32x32 tile transpose. Grid: S * 24 * 8 blocks.
// ---------------------------------------------------------------------------
__global__ __launch_bounds__(256) void convB_kernel(
    const float* __restrict__ in, half_t* __restrict__ out)
{
  __shared__ float tile[32][36];
  int b  = blockIdx.x;
  int s  = b / 192;
  int r  = b % 192;
  int kt = r / 8;
  int nt = r % 8;
  int t  = threadIdx.x;

  int kk  = t >> 3;
  int nn4 = (t & 7) * 4;
  float4 v = *(const float4*)(in + ((size_t)s * NE + kt * 32 + kk) * NG + nt * 32 + nn4);
  tile[kk][nn4 + 0] = v.x; tile[kk][nn4 + 1] = v.y;
  tile[kk][nn4 + 2] = v.z; tile[kk][nn4 + 3] = v.w;
  __syncthreads();

  int nn = t >> 3;
  int kq = (t & 7) * 4;
  half4v o;
#pragma unroll
  for (int j = 0; j < 4; ++j) o[j] = (half_t)tile[kq + j][nn];
  *(half4v*)(out + ((size_t)s * NG + nt * 32 + nn) * NE + kt * 32 + kq) = o;
}

// ---------------------------------------------------------------------------
// gemm_mfma SPLIT-K: Upart[ks][s,m,n] = text[s,m,kslice] . Bf16[s,n,kslice]
// (+ bias if ks==0). R7-proven structure: 64m x 128n tile, BK=64, 4 waves
// (2m x 2n), 24KB LDS, 2-barrier loop — but only 6 K-steps per block and
// 1760 blocks (88 stocks x 10 tiles x 2 k-slices) => ~7 blocks/CU.
// A reg-staged f32->f16 with XOR-swizzled ds_write (chunk c -> c^(row&7));
// B via global_load_lds with inverse-swizzled per-lane source.
// ---------------------------------------------------------------------------
__global__ __launch_bounds__(256) void gemm_mfma_kernel(
    const float*  __restrict__ text,  // [S,300,768] f32
    const half_t* __restrict__ Bf16,  // [S,256,768] f16 (n-major, k contig)
    const float*  __restrict__ bias,  // [S,256]
    float* __restrict__ Upart)        // [NKS][S,300,256]
{
  __shared__ uint4 smem4[1536];       // 24 KiB: A 8K @0, B 16K @8192
  char* smem = (char*)smem4;

  int b   = blockIdx.x;
  int swz = (b & 7) * 220 + (b >> 3);   // 1760 = 8*220, bijective XCD swizzle
  int s    = swz / 20;
  int rem  = swz % 20;
  int ks   = rem / 10;                  // k-slice 0..1
  int rr_  = rem % 10;
  int m0   = (rr_ >> 1) * 64;           // 5 m-tiles (rows 300..319 zeroed)
  int n0   = (rr_ & 1) * 128;
  int kbase = ks * (NE / NKS);          // 0 or 384

  int tid = threadIdx.x;
  int w = tid >> 6, l = tid & 63;
  int wm = w >> 1, wn = w & 1;
  int lr = l & 15, lk = l >> 4;       // fragment row, k-group

  const float*  At = text + (size_t)s * NM * NE;
  const half_t* Bb = Bf16 + ((size_t)s * NG + n0) * NE;

  f32x4 acc[2][4];
#pragma unroll
  for (int i = 0; i < 2; ++i)
#pragma unroll
    for (int j = 0; j < 4; ++j) acc[i][j] = (f32x4){0.f, 0.f, 0.f, 0.f};

  for (int step = 0; step < (NE / NKS) / 64; ++step) {
    int k0 = kbase + step * 64;
    // stage B: 128 rows x 64 k = 16KB (4 gload calls), inverse-swz source
#pragma unroll
    for (int j = 0; j < 4; ++j) {
      int ci  = j * 256 + tid;
      int row = ci >> 3;
      int c   = (ci & 7) ^ (row & 7);
      gload_lds16(Bb + (size_t)row * NE + k0 + c * 8,
                  smem + 8192 + j * 4096 + w * 1024);
    }
    // stage A: 64 rows x 64 k, f32 global -> f16 -> swizzled ds_write_b128
#pragma unroll
    for (int j = 0; j < 2; ++j) {
      int idx = j * 256 + tid;
      int row = idx >> 3, c = idx & 7;
      int m   = m0 + row;
      half8 av;
      if (m < NM) {
        const float* p = At + (size_t)m * NE + k0 + c * 8;
        float4 x = *(const float4*)p;
        float4 y = *(const float4*)(p + 4);
        av[0] = (half_t)x.x; av[1] = (half_t)x.y;
        av[2] = (half_t)x.z; av[3] = (half_t)x.w;
        av[4] = (half_t)y.x; av[5] = (half_t)y.y;
        av[6] = (half_t)y.z; av[7] = (half_t)y.w;
      } else {
#pragma unroll
        for (int q = 0; q < 8; ++q) av[q] = (half_t)0.f;
      }
      *(half8*)(smem + row * 128 + ((c ^ (row & 7)) * 16)) = av;
    }
    __syncthreads();   // drains vmcnt (gload) + lgkmcnt (ds_write)

#pragma unroll
    for (int kk = 0; kk < 2; ++kk) {
      half8 af[2], bf[4];
#pragma unroll
      for (int fm = 0; fm < 2; ++fm) {
        int rw = wm * 32 + fm * 16 + lr;
        int cc = (kk * 4 + lk) ^ (rw & 7);
        af[fm] = *(const half8*)(smem + rw * 128 + cc * 16);
      }
#pragma unroll
      for (int fn = 0; fn < 4; ++fn) {
        int rw = wn * 64 + fn * 16 + lr;
        int cc = (kk * 4 + lk) ^ (rw & 7);
        bf[fn] = *(const half8*)(smem + 8192 + rw * 128 + cc * 16);
      }
#pragma unroll
      for (int fm = 0; fm < 2; ++fm)
#pragma unroll
        for (int fn = 0; fn < 4; ++fn)
          acc[fm][fn] = __builtin_amdgcn_mfma_f32_16x16x32_f16(
              af[fm], bf[fn], acc[fm][fn], 0, 0, 0);
    }
    __syncthreads();
  }

  // epilogue: D row = lk*4+e, col = lr (m89 layout); bias only on slice 0
  float* U = Upart + (size_t)ks * ((size_t)NS * NM * NG);
#pragma unroll
  for (int fn = 0; fn < 4; ++fn) {
    int col = n0 + wn * 64 + fn * 16 + lr;
    float bv = (ks == 0) ? bias[(size_t)s * NG + col] : 0.f;
#pragma unroll
    for (int fm = 0; fm < 2; ++fm) {
      int mbase = m0 + wm * 32 + fm * 16 + lk * 4;
#pragma unroll
      for (int e = 0; e < 4; ++e) {
        int m = mbase + e;
        if (m < NM)
          U[((size_t)s * NM + m) * NG + col] = acc[fm][fn][e] + bv;
      }
    }
  }
}

// ---------------------------------------------------------------------------
// TimeLSTM + text attention FUSED. One wave per (stock, day) — barrier-free.
// u read directly from the two split-K partials (global, L2-warm, coalesced
// 256B/wave) — loads issued before the 32-iter dot chain so VALU hides them.
// No u LDS staging (frees 30KB -> more blocks/CU).
// ---------------------------------------------------------------------------
__global__ __launch_bounds__(64) void lstm_attn_kernel(
    const float* __restrict__ u,       // [NKS][S, L*T, 256] f32 partials
    const float* __restrict__ time_in, // [S, L, T]
    const float* __restrict__ Wdw,  const float* __restrict__ Wdb,
    const float* __restrict__ Wallw, const float* __restrict__ Wallb,
    const float* __restrict__ tW1w, const float* __restrict__ tW1b,
    const float* __restrict__ tW2w, const float* __restrict__ tW2b,
    const float* __restrict__ tVw,  const float* __restrict__ tVb,
    float* __restrict__ day_vec)       // [S, L, H]
{
  int bid = blockIdx.x;                // s*NL + l
  int s = bid / NL;
  int j = threadIdx.x;                 // 0..63

  __shared__ float   hist[NT][NH];     // 7.5 KiB
  __shared__ float   ts_s[NT];
  __shared__ half2_t h2_s[NH / 2];
  __shared__ half2_t c2_s[NH / 2];

  const size_t UP = (size_t)NS * NM * NG;
  const float* up0 = u + (size_t)bid * NT * NG;
  const float* up1 = up0 + UP;

  if (j < NT) ts_s[j] = time_in[(size_t)bid * NT + j];
  ((half_t*)h2_s)[j] = (half_t)0.f;
  ((half_t*)c2_s)[j] = (half_t)0.f;

  // weights -> packed f16 pairs in VGPRs
  const float* Wa  = Wallw + (size_t)s * NH * NG;
  const float* Wdp = Wdw   + (size_t)s * NH * NH;
  half2_t wf[32], wi[32], wo[32], wg[32], wd[32];
#pragma unroll
  for (int k2 = 0; k2 < 32; ++k2) {
    wf[k2] = mk_h2(Wa[(2*k2) * NG + j],        Wa[(2*k2+1) * NG + j]);
    wi[k2] = mk_h2(Wa[(2*k2) * NG + 64 + j],   Wa[(2*k2+1) * NG + 64 + j]);
    wo[k2] = mk_h2(Wa[(2*k2) * NG + 128 + j],  Wa[(2*k2+1) * NG + 128 + j]);
    wg[k2] = mk_h2(Wa[(2*k2) * NG + 192 + j],  Wa[(2*k2+1) * NG + 192 + j]);
    wd[k2] = mk_h2(Wdp[(2*k2) * NH + j],       Wdp[(2*k2+1) * NH + j]);
  }
  float bf = Wallb[(size_t)s * NG + j];
  float bi = Wallb[(size_t)s * NG + 64 + j];
  float bo = Wallb[(size_t)s * NG + 128 + j];
  float bg = Wallb[(size_t)s * NG + 192 + j];
  float bd = Wdb[(size_t)s * NH + j];

  float c_my = 0.f;
  for (int t = 0; t < NT; ++t) {
    // issue u-partial loads first; dot chain below hides their latency
    int o = t * NG + j;
    float u0f = up0[o],       u1f = up1[o];
    float u0i = up0[o + 64],  u1i = up1[o + 64];
    float u0o = up0[o + 128], u1o = up1[o + 128];
    float u0g = up0[o + 192], u1g = up1[o + 192];

    float dotf = 0.f, doti = 0.f, doto = 0.f, dotg = 0.f, dotd = 0.f;
#pragma unroll
    for (int k2 = 0; k2 < 32; ++k2) {
      half2_t hv = h2_s[k2];
      half2_t cv = c2_s[k2];
      dotf = fdot2(hv, wf[k2], dotf);
      doti = fdot2(hv, wi[k2], doti);
      doto = fdot2(hv, wo[k2], doto);
      dotg = fdot2(hv, wg[k2], dotg);
      dotd = fdot2(cv, wd[k2], dotd);
    }
    float f  = fsigmoid(dotf + bf + u0f + u1f);   // all-sigmoid gates
    float ii = fsigmoid(doti + bi + u0i + u1i);
    float o_ = fsigmoid(doto + bo + u0o + u1o);
    float gg = fsigmoid(dotg + bg + u0g + u1g);
    float cadj = c_my + ftanh(dotd + bd) * (ts_s[t] - 1.f);
    float cn = fmaf(f, cadj, ii * gg);
    c_my = cn;
    float hn = o_ * ftanh(cn);
    ((half_t*)h2_s)[j] = (half_t)hn;
    ((half_t*)c2_s)[j] = (half_t)cn;
    hist[t][j] = hn;                    // keep history in LDS (f32)
  }

  // ---- text attention over T (same wave; hist complete, ds-ordered) ----
  const float* tW1p = tW1w + (size_t)s * NH * NH;
  const float* tW2p = tW2w + (size_t)s * NH * NH;

  float tw2c[NH];                       // tW2 column j in regs
#pragma unroll
  for (int h = 0; h < NH; ++h) tw2c[h] = tW2p[(size_t)h * NH + j];

  float a1 = tW1b[(size_t)s * NH + j];
  {
    const float4* h4 = (const float4*)&hist[NT - 1][0];
#pragma unroll
    for (int q = 0; q < NH / 4; ++q) {
      float4 v = h4[q];
      a1 = fmaf(v.x, tW1p[(size_t)(4*q+0) * NH + j], a1);
      a1 = fmaf(v.y, tW1p[(size_t)(4*q+1) * NH + j], a1);
      a1 = fmaf(v.z, tW1p[(size_t)(4*q+2) * NH + j], a1);
      a1 = fmaf(v.w, tW1p[(size_t)(4*q+3) * NH + j], a1);
    }
  }
  float b2k = tW2b[(size_t)s * NH + j];
  float tv  = tVw[(size_t)s * NH + j];
  float tvb = tVb[s];

  float sc[NT];
#pragma unroll
  for (int t = 0; t < NT; ++t) {
    float a2 = b2k;
    const float4* h4 = (const float4*)&hist[t][0];
#pragma unroll
    for (int q = 0; q < NH / 4; ++q) {
      float4 v = h4[q];
      a2 = fmaf(v.x, tw2c[4*q+0], a2);
      a2 = fmaf(v.y, tw2c[4*q+1], a2);
      a2 = fmaf(v.z, tw2c[4*q+2], a2);
      a2 = fmaf(v.w, tw2c[4*q+3], a2);
    }
    float v = ftanh(a1 + a2) * tv;
#pragma unroll
    for (int off = 32; off >= 1; off >>= 1) v += __shfl_xor(v, off);
    sc[t] = v + tvb;
  }
  float mx = sc[0];
#pragma unroll
  for (int t = 1; t < NT; ++t) mx = fmaxf(mx, sc[t]);
  float sum = 0.f;
#pragma unroll
  for (int t = 0; t < NT; ++t) { sc[t] = __expf(sc[t] - mx); sum += sc[t]; }
  float inv = __builtin_amdgcn_rcpf(sum);
  float dv = 0.f;
#pragma unroll
  for (int t = 0; t < NT; ++t) dv = fmaf(sc[t] * inv, hist[t][j], dv);
  day_vec[(size_t)bid * NH + j] = dv;
}

// ---------------------------------------------------------------------------
// day LSTM + day attention + pred head. One block per stock.
// ---------------------------------------------------------------------------
__global__ __launch_bounds__(256) void day_head_kernel(
    const float* __restrict__ day_vec, // [S, L, H]
    const float* __restrict__ ihw, const float* __restrict__ ihb,
    const float* __restrict__ hhb,
    const float* __restrict__ dW1w, const float* __restrict__ dW1b,
    const float* __restrict__ dW2w, const float* __restrict__ dW2b,
    const float* __restrict__ dVw,  const float* __restrict__ dVb,
    const float* __restrict__ predw, const float* __restrict__ predb,
    float* __restrict__ out)           // [S]
{
  int s = blockIdx.x;
  int g = threadIdx.x;
  int j = g & 63;
  int q = g >> 6;

  __shared__ float dv_s[NL][NH];
  __shared__ float gl[NL][NG];
  __shared__ float hd[NL][NH];

  for (int i = g; i < NL * NH; i += 256)
    ((float*)dv_s)[i] = day_vec[(size_t)s * NL * NH + i];
  __syncthreads();

  float ihcol[NH];
#pragma unroll
  for (int k = 0; k < NH; ++k)
    ihcol[k] = ihw[((size_t)s * NH + k) * NG + g];
  float bias = ihb[(size_t)s * NG + g] + hhb[(size_t)s * NG + g];

  bool is_gpart = (g >= 128 && g < 192);
  for (int l = 0; l < NL; ++l) {
    float acc = bias;
#pragma unroll
    for (int k = 0; k < NH; ++k) acc = fmaf(dv_s[l][k], ihcol[k], acc);
    gl[l][g] = is_gpart ? ftanh(acc) : fsigmoid(acc);
  }
  __syncthreads();
  for (int l = q; l < NL; l += 4) {
    float cd = gl[l][j] * gl[l][128 + j];       // sig(i)*tanh(g)
    hd[l][j] = gl[l][192 + j] * ftanh(cd);      // sig(o)*tanh(c)
  }
  __syncthreads();

  if (g < 64) {
    int k = g;
    float dw1c[NH], dw2c[NH];
#pragma unroll
    for (int h = 0; h < NH; ++h) {
      dw1c[h] = dW1w[((size_t)s * NH + h) * NH + k];
      dw2c[h] = dW2w[((size_t)s * NH + h) * NH + k];
    }
    float b1 = dW1b[(size_t)s * NH + k];
    float b2 = dW2b[(size_t)s * NH + k];
    float dv = dVw[(size_t)s * NH + k];
    float dvb = dVb[s];

    float sc[NL];
#pragma unroll
    for (int l = 0; l < NL; ++l) {
      float x1 = b1, x2 = b2;
#pragma unroll
      for (int h = 0; h < NH; ++h) {
        x1 = fmaf(hd[l][h], dw1c[h], x1);
        x2 = fmaf(hd[l][h], dw2c[h], x2);
      }
      float v = ftanh(x1 + x2) * dv;
#pragma unroll
      for (int off = 32; off >= 1; off >>= 1) v += __shfl_xor(v, off);
      sc[l] = v + dvb;
    }
    float mx = sc[0];
#pragma unroll
    for (int l = 1; l < NL; ++l) mx = fmaxf(mx, sc[l]);
    float sum = 0.f;
#pragma unroll
    for (int l = 0; l < NL; ++l) { sc[l] = __expf(sc[l] - mx); sum += sc[l]; }
    float inv = __builtin_amdgcn_rcpf(sum);
    float sv = 0.f;
#pragma unroll
    for (int l = 0; l < NL; ++l) sv = fmaf(sc[l] * inv, hd[l][k], sv);

    float p = sv * predw[k];
#pragma unroll
    for (int off = 32; off >= 1; off >>= 1) p += __shfl_xor(p, off);
    if (k == 0) {
      float x = p + predb[0];
      out[s] = (x >= 0.f) ? x : 0.01f * x;
    }
  }
}

// ---------------------------------------------------------------------------
extern "C" void kernel_launch(void* const* d_in, const int* in_sizes, int n_in,
                              void* d_out, int out_size, void* d_ws, size_t ws_size,
                              hipStream_t stream) {
  (void)in_sizes; (void)n_in; (void)out_size; (void)ws_size;

  const float* text    = (const float*)d_in[0];
  const float* time_in = (const float*)d_in[1];
  const float* Wdw     = (const float*)d_in[2];
  const float* Wdb     = (const float*)d_in[3];
  const float* Wallw   = (const float*)d_in[4];
  const float* Wallb   = (const float*)d_in[5];
  const float* Uallw   = (const float*)d_in[6];
  const float* Uallb   = (const float*)d_in[7];
  const float* tW1w    = (const float*)d_in[8];
  const float* tW1b    = (const float*)d_in[9];
  const float* tW2w    = (const float*)d_in[10];
  const float* tW2b    = (const float*)d_in[11];
  const float* tVw     = (const float*)d_in[12];
  const float* tVb     = (const float*)d_in[13];
  const float* ihw     = (const float*)d_in[14];
  const float* ihb     = (const float*)d_in[15];
  const float* hhb     = (const float*)d_in[16];
  const float* dW1w    = (const float*)d_in[17];
  const float* dW1b    = (const float*)d_in[18];
  const float* dW2w    = (const float*)d_in[19];
  const float* dW2b    = (const float*)d_in[20];
  const float* dVw     = (const float*)d_in[21];
  const float* dVb     = (const float*)d_in[22];
  const float* predw   = (const float*)d_in[23];
  const float* predb   = (const float*)d_in[24];

  float* ws      = (float*)d_ws;
  float* u_part  = ws;                                   // 2*S*300*256 f32 (54MB)
  float* day_vec = u_part + (size_t)NKS * NS * NM * NG;  // S*L*H f32
  half_t* Bf16   = (half_t*)(day_vec + (size_t)NS * NL * NH); // S*256*768 f16

  convB_kernel<<<NS * 192, 256, 0, stream>>>(Uallw, Bf16);
  gemm_mfma_kernel<<<NS * 10 * NKS, 256, 0, stream>>>(text, Bf16, Uallb, u_part);
  lstm_attn_kernel<<<NS * NL, 64, 0, stream>>>(u_part, time_in, Wdw, Wdb,
                                               Wallw, Wallb,
                                               tW1w, tW1b, tW2w, tW2b,
                                               tVw, tVb, day_vec);
  day_head_kernel<<<NS, 256, 0, stream>>>(day_vec, ihw, ihb, hhb,
                                          dW1w, dW1b, dW2w, dW2b, dVw, dVb,
                                          predw, predb, (float*)d_out);
}

// Round 11
// 110.391 us; speedup vs baseline: 1.2037x; 1.1933x over previous
//
#include <hip/hip_runtime.h>
#include <cmath>

#define NS 88
#define NL 10
#define NT 30
#define NE 768
#define NH 64
#define NG 256   // 4*H
#define NM 300   // L*T

typedef _Float16 half_t;
typedef __attribute__((ext_vector_type(2))) _Float16 half2_t;
typedef __attribute__((ext_vector_type(8))) _Float16 half8;
typedef __attribute__((ext_vector_type(4))) _Float16 half4v;
typedef __attribute__((ext_vector_type(4))) float f32x4;

__device__ inline void gload_lds16(const void* g, void* l) {
  __builtin_amdgcn_global_load_lds(
      (const __attribute__((address_space(1))) unsigned int*)g,
      (__attribute__((address_space(3))) unsigned int*)l, 16, 0, 0);
}

#define WAITV(N) asm volatile("s_waitcnt vmcnt(" #N ")" ::: "memory")
#define LGKM0    asm volatile("s_waitcnt lgkmcnt(0)" ::: "memory")

// fast sigmoid/tanh: v_exp_f32 + v_rcp_f32
__device__ inline float fsigmoid(float x) {
  return __builtin_amdgcn_rcpf(1.f + __expf(-x));
}
__device__ inline float ftanh(float x) {
  float e = __expf(2.f * x);
  return 1.f - 2.f * __builtin_amdgcn_rcpf(e + 1.f);
}

#if __has_builtin(__builtin_amdgcn_fdot2)
__device__ inline float fdot2(half2_t a, half2_t b, float c) {
  return __builtin_amdgcn_fdot2(a, b, c, false);   // v_dot2_f32_f16
}
#else
__device__ inline float fdot2(half2_t a, half2_t b, float c) {
  return fmaf((float)a[1], (float)b[1], fmaf((float)a[0], (float)b[0], c));
}
#endif

__device__ inline half2_t mk_h2(float a, float b) {
  half2_t r; r[0] = (half_t)a; r[1] = (half_t)b; return r;
}

// ---------------------------------------------------------------------------
// convB: Uall_w fp32 [S,768,256] -> fp16 transposed [S,256,768] (n-major,
// k contiguous). LDS 32x32 tile transpose. Grid: S * 24 * 8 blocks.
// ---------------------------------------------------------------------------
__global__ __launch_bounds__(256) void convB_kernel(
    const float* __restrict__ in, half_t* __restrict__ out)
{
  __shared__ float tile[32][36];
  int b  = blockIdx.x;
  int s  = b / 192;
  int r  = b % 192;
  int kt = r / 8;
  int nt = r % 8;
  int t  = threadIdx.x;

  int kk  = t >> 3;
  int nn4 = (t & 7) * 4;
  float4 v = *(const float4*)(in + ((size_t)s * NE + kt * 32 + kk) * NG + nt * 32 + nn4);
  tile[kk][nn4 + 0] = v.x; tile[kk][nn4 + 1] = v.y;
  tile[kk][nn4 + 2] = v.z; tile[kk][nn4 + 3] = v.w;
  __syncthreads();

  int nn = t >> 3;
  int kq = (t & 7) * 4;
  half4v o;
#pragma unroll
  for (int j = 0; j < 4; ++j) o[j] = (half_t)tile[kq + j][nn];
  *(half4v*)(out + ((size_t)s * NG + nt * 32 + nn) * NE + kt * 32 + kq) = o;
}

// ---------------------------------------------------------------------------
// gemm_mfma: U[s,m,n] = text[s,m,:] . Bf16[s,n,:] + bias[s,n]
// R7 geometry (64m x 128n tile, BK=64, 4 waves 2m x 2n, 880 blocks) with a
// REAL pipeline: double-buffered LDS (48KB, 3 blocks/CU), B prefetch depth 1
// (gload_lds), A prefetch depth 2 (f32 reg loads, two named sets), counted
// s_waitcnt vmcnt(4) at the barrier — A(k+2) loads stay in flight across it.
// Issue order B-before-A makes the FIFO vmcnt counting safe.
// ---------------------------------------------------------------------------
__global__ __launch_bounds__(256) void gemm_mfma_kernel(
    const float*  __restrict__ text,  // [S,300,768] f32
    const half_t* __restrict__ Bf16,  // [S,256,768] f16 (n-major, k contig)
    const float*  __restrict__ bias,  // [S,256]
    float* __restrict__ U)            // [S,300,256]
{
  __shared__ uint4 smem4[3072];       // 48 KiB: A0@0 A1@8K B0@16K B1@32K
  char* smem = (char*)smem4;

  int b   = blockIdx.x;
  int swz = (b & 7) * 110 + (b >> 3);   // 880 = 8*110, bijective XCD swizzle
  int s   = swz / 10;
  int rr_ = swz % 10;
  int m0  = (rr_ >> 1) * 64;            // 5 m-tiles (rows 300..319 zeroed)
  int n0  = (rr_ & 1) * 128;

  int tid = threadIdx.x;
  int w = tid >> 6, l = tid & 63;
  int wm = w >> 1, wn = w & 1;
  int lr = l & 15, lk = l >> 4;       // fragment row, k-group

  const float*  At = text + (size_t)s * NM * NE;
  const half_t* Bb = Bf16 + ((size_t)s * NG + n0) * NE;

  f32x4 acc[2][4];
#pragma unroll
  for (int i = 0; i < 2; ++i)
#pragma unroll
    for (int j = 0; j < 4; ++j) acc[i][j] = (f32x4){0.f, 0.f, 0.f, 0.f};

  float4 ra0[2][2], ra1[2][2];        // two named A-stage register sets

#define STAGE_B(K)                                                           \
  {                                                                          \
    char* Bdst = smem + 16384 + ((K) & 1) * 16384;                           \
    _Pragma("unroll")                                                        \
    for (int j = 0; j < 4; ++j) {                                            \
      int ci  = j * 256 + tid;                                               \
      int row = ci >> 3;                                                     \
      int c   = (ci & 7) ^ (row & 7);                                        \
      gload_lds16(Bb + (size_t)row * NE + (K) * 64 + c * 8,                  \
                  Bdst + j * 4096 + w * 1024);                               \
    }                                                                        \
  }

#define STAGE_A_ISSUE(K, RA)                                                 \
  {                                                                          \
    _Pragma("unroll")                                                        \
    for (int j = 0; j < 2; ++j) {                                            \
      int idx = j * 256 + tid;                                               \
      int row = idx >> 3;                                                    \
      int m   = m0 + row;                                                    \
      const float* p = At + (size_t)(m < NM ? m : NM - 1) * NE + (K) * 64 +  \
                       (idx & 7) * 8;                                        \
      RA[j][0] = *(const float4*)p;                                          \
      RA[j][1] = *(const float4*)(p + 4);                                    \
    }                                                                        \
  }

#define STAGE_A_WRITE(K, RA)                                                 \
  {                                                                          \
    char* Adst = smem + ((K) & 1) * 8192;                                    \
    _Pragma("unroll")                                                        \
    for (int j = 0; j < 2; ++j) {                                            \
      int idx = j * 256 + tid;                                               \
      int row = idx >> 3, c = idx & 7;                                       \
      int m   = m0 + row;                                                    \
      half8 av;                                                              \
      av[0] = (half_t)RA[j][0].x; av[1] = (half_t)RA[j][0].y;                \
      av[2] = (half_t)RA[j][0].z; av[3] = (half_t)RA[j][0].w;                \
      av[4] = (half_t)RA[j][1].x; av[5] = (half_t)RA[j][1].y;                \
      av[6] = (half_t)RA[j][1].z; av[7] = (half_t)RA[j][1].w;                \
      if (m >= NM) {                                                         \
        _Pragma("unroll")                                                    \
        for (int q = 0; q < 8; ++q) av[q] = (half_t)0.f;                     \
      }                                                                      \
      *(half8*)(Adst + row * 128 + ((c ^ (row & 7)) * 16)) = av;             \
    }                                                                        \
  }

#define COMPUTE(K)                                                           \
  {                                                                          \
    char* Ac = smem + ((K) & 1) * 8192;                                      \
    char* Bc = smem + 16384 + ((K) & 1) * 16384;                             \
    _Pragma("unroll")                                                        \
    for (int kk = 0; kk < 2; ++kk) {                                         \
      half8 af[2], bf[4];                                                    \
      _Pragma("unroll")                                                      \
      for (int fm = 0; fm < 2; ++fm) {                                       \
        int rw = wm * 32 + fm * 16 + lr;                                     \
        int cc = (kk * 4 + lk) ^ (rw & 7);                                   \
        af[fm] = *(const half8*)(Ac + rw * 128 + cc * 16);                   \
      }                                                                      \
      _Pragma("unroll")                                                      \
      for (int fn = 0; fn < 4; ++fn) {                                       \
        int rw = wn * 64 + fn * 16 + lr;                                     \
        int cc = (kk * 4 + lk) ^ (rw & 7);                                   \
        bf[fn] = *(const half8*)(Bc + rw * 128 + cc * 16);                   \
      }                                                                      \
      _Pragma("unroll")                                                      \
      for (int fm = 0; fm < 2; ++fm)                                         \
        _Pragma("unroll")                                                    \
        for (int fn = 0; fn < 4; ++fn)                                       \
          acc[fm][fn] = __builtin_amdgcn_mfma_f32_16x16x32_f16(              \
              af[fm], bf[fn], acc[fm][fn], 0, 0, 0);                         \
    }                                                                        \
  }

  // iter k: stageB(k+1) | issueA(k+2)->RA_I | compute(k) | writeA(k+1)<-RA_W
  //         | vmcnt(4) [B(k+1) done, A(k+2) in flight] | lgkm0 | barrier
#define BODY(K, RA_I, RA_W)                                                  \
  {                                                                          \
    if ((K) + 1 < 12) STAGE_B((K) + 1);                                      \
    if ((K) + 2 < 12) STAGE_A_ISSUE((K) + 2, RA_I);                          \
    COMPUTE(K);                                                              \
    if ((K) + 1 < 12) STAGE_A_WRITE((K) + 1, RA_W);                          \
    if ((K) + 2 < 12) { WAITV(4); } else if ((K) + 1 < 12) { WAITV(0); }     \
    if ((K) + 1 < 12) { LGKM0; __builtin_amdgcn_s_barrier(); }               \
  }

  // prologue: B(0) + A(0),A(1) in flight; publish buf0
  STAGE_B(0);
  STAGE_A_ISSUE(0, ra0);
  STAGE_A_ISSUE(1, ra1);
  STAGE_A_WRITE(0, ra0);   // implicit vmcnt(4): retires B(0)+A(0), A(1) flies
  LGKM0;
  __builtin_amdgcn_s_barrier();

#pragma unroll 1
  for (int kb = 0; kb < 12; kb += 2) {
    BODY(kb, ra0, ra1);          // even: issue->ra0, write from ra1
    BODY(kb + 1, ra1, ra0);      // odd:  issue->ra1, write from ra0
  }
#undef STAGE_B
#undef STAGE_A_ISSUE
#undef STAGE_A_WRITE
#undef COMPUTE
#undef BODY

  // epilogue: D row = lk*4+e, col = lr (m89 layout); add bias, f32 store
#pragma unroll
  for (int fn = 0; fn < 4; ++fn) {
    int col = n0 + wn * 64 + fn * 16 + lr;
    float bv = bias[(size_t)s * NG + col];
#pragma unroll
    for (int fm = 0; fm < 2; ++fm) {
      int mbase = m0 + wm * 32 + fm * 16 + lk * 4;
#pragma unroll
      for (int e = 0; e < 4; ++e) {
        int m = mbase + e;
        if (m < NM)
          U[((size_t)s * NM + m) * NG + col] = acc[fm][fn][e] + bv;
      }
    }
  }
}

// ---------------------------------------------------------------------------
// TimeLSTM + text attention FUSED (R7 version). One wave per (stock, day).
// u tile staged once via global_load_lds (per-lane source); barrier-free.
// ---------------------------------------------------------------------------
__global__ __launch_bounds__(64) void lstm_attn_kernel(
    const float* __restrict__ u,       // [S, L*T, 256] f32
    const float* __restrict__ time_in, // [S, L, T]
    const float* __restrict__ Wdw,  const float* __restrict__ Wdb,
    const float* __restrict__ Wallw, const float* __restrict__ Wallb,
    const float* __restrict__ tW1w, const float* __restrict__ tW1b,
    const float* __restrict__ tW2w, const float* __restrict__ tW2b,
    const float* __restrict__ tVw,  const float* __restrict__ tVb,
    float* __restrict__ day_vec)       // [S, L, H]
{
  int bid = blockIdx.x;                // s*NL + l
  int s = bid / NL;
  int j = threadIdx.x;                 // 0..63

  __shared__ float   u_s[NT * NG];     // 30 KiB
  __shared__ float   hist[NT][NH];     // 7.5 KiB
  __shared__ float   ts_s[NT];
  __shared__ half2_t h2_s[NH / 2];
  __shared__ half2_t c2_s[NH / 2];

  // stage u tile: 30 rows x 1KB, per-lane source (lane j -> bytes 16j..16j+16)
  const float* u_base = u + (size_t)bid * NT * NG;
#pragma unroll
  for (int i = 0; i < NT; ++i)
    gload_lds16(u_base + i * NG + j * 4, (char*)u_s + i * 1024);

  if (j < NT) ts_s[j] = time_in[(size_t)bid * NT + j];
  ((half_t*)h2_s)[j] = (half_t)0.f;
  ((half_t*)c2_s)[j] = (half_t)0.f;

  // weights -> packed f16 pairs in VGPRs
  const float* Wa  = Wallw + (size_t)s * NH * NG;
  const float* Wdp = Wdw   + (size_t)s * NH * NH;
  half2_t wf[32], wi[32], wo[32], wg[32], wd[32];
#pragma unroll
  for (int k2 = 0; k2 < 32; ++k2) {
    wf[k2] = mk_h2(Wa[(2*k2) * NG + j],        Wa[(2*k2+1) * NG + j]);
    wi[k2] = mk_h2(Wa[(2*k2) * NG + 64 + j],   Wa[(2*k2+1) * NG + 64 + j]);
    wo[k2] = mk_h2(Wa[(2*k2) * NG + 128 + j],  Wa[(2*k2+1) * NG + 128 + j]);
    wg[k2] = mk_h2(Wa[(2*k2) * NG + 192 + j],  Wa[(2*k2+1) * NG + 192 + j]);
    wd[k2] = mk_h2(Wdp[(2*k2) * NH + j],       Wdp[(2*k2+1) * NH + j]);
  }
  float bf = Wallb[(size_t)s * NG + j];
  float bi = Wallb[(size_t)s * NG + 64 + j];
  float bo = Wallb[(size_t)s * NG + 128 + j];
  float bg = Wallb[(size_t)s * NG + 192 + j];
  float bd = Wdb[(size_t)s * NH + j];

  // drain global_load_lds before reading u_s (single wave: no barrier)
  asm volatile("s_waitcnt vmcnt(0)" ::: "memory");

  float c_my = 0.f;
  for (int t = 0; t < NT; ++t) {
    float accf = bf + u_s[t * NG + j];
    float acci = bi + u_s[t * NG + 64 + j];
    float acco = bo + u_s[t * NG + 128 + j];
    float accg = bg + u_s[t * NG + 192 + j];
    float accd = bd;
#pragma unroll
    for (int k2 = 0; k2 < 32; ++k2) {
      half2_t hv = h2_s[k2];
      half2_t cv = c2_s[k2];
      accf = fdot2(hv, wf[k2], accf);
      acci = fdot2(hv, wi[k2], acci);
      acco = fdot2(hv, wo[k2], acco);
      accg = fdot2(hv, wg[k2], accg);
      accd = fdot2(cv, wd[k2], accd);
    }
    float f  = fsigmoid(accf);          // reference: all-sigmoid gates
    float ii = fsigmoid(acci);
    float o  = fsigmoid(acco);
    float gg = fsigmoid(accg);
    float cadj = c_my + ftanh(accd) * (ts_s[t] - 1.f);
    float cn = fmaf(f, cadj, ii * gg);
    c_my = cn;
    float hn = o * ftanh(cn);
    ((half_t*)h2_s)[j] = (half_t)hn;
    ((half_t*)c2_s)[j] = (half_t)cn;
    hist[t][j] = hn;                    // keep history in LDS (f32)
  }

  // ---- text attention over T (same wave; hist complete, ds-ordered) ----
  const float* tW1p = tW1w + (size_t)s * NH * NH;
  const float* tW2p = tW2w + (size_t)s * NH * NH;

  float tw2c[NH];                       // tW2 column j in regs
#pragma unroll
  for (int h = 0; h < NH; ++h) tw2c[h] = tW2p[(size_t)h * NH + j];

  float a1 = tW1b[(size_t)s * NH + j];
  {
    const float4* h4 = (const float4*)&hist[NT - 1][0];
#pragma unroll
    for (int q = 0; q < NH / 4; ++q) {
      float4 v = h4[q];
      a1 = fmaf(v.x, tW1p[(size_t)(4*q+0) * NH + j], a1);
      a1 = fmaf(v.y, tW1p[(size_t)(4*q+1) * NH + j], a1);
      a1 = fmaf(v.z, tW1p[(size_t)(4*q+2) * NH + j], a1);
      a1 = fmaf(v.w, tW1p[(size_t)(4*q+3) * NH + j], a1);
    }
  }
  float b2k = tW2b[(size_t)s * NH + j];
  float tv  = tVw[(size_t)s * NH + j];
  float tvb = tVb[s];

  float sc[NT];
#pragma unroll
  for (int t = 0; t < NT; ++t) {
    float a2 = b2k;
    const float4* h4 = (const float4*)&hist[t][0];
#pragma unroll
    for (int q = 0; q < NH / 4; ++q) {
      float4 v = h4[q];
      a2 = fmaf(v.x, tw2c[4*q+0], a2);
      a2 = fmaf(v.y, tw2c[4*q+1], a2);
      a2 = fmaf(v.z, tw2c[4*q+2], a2);
      a2 = fmaf(v.w, tw2c[4*q+3], a2);
    }
    float v = ftanh(a1 + a2) * tv;
#pragma unroll
    for (int off = 32; off >= 1; off >>= 1) v += __shfl_xor(v, off);
    sc[t] = v + tvb;
  }
  float mx = sc[0];
#pragma unroll
  for (int t = 1; t < NT; ++t) mx = fmaxf(mx, sc[t]);
  float sum = 0.f;
#pragma unroll
  for (int t = 0; t < NT; ++t) { sc[t] = __expf(sc[t] - mx); sum += sc[t]; }
  float inv = __builtin_amdgcn_rcpf(sum);
  float dv = 0.f;
#pragma unroll
  for (int t = 0; t < NT; ++t) dv = fmaf(sc[t] * inv, hist[t][j], dv);
  day_vec[(size_t)bid * NH + j] = dv;
}

// ---------------------------------------------------------------------------
// day LSTM + day attention + pred head. One block per stock.
// ---------------------------------------------------------------------------
__global__ __launch_bounds__(256) void day_head_kernel(
    const float* __restrict__ day_vec, // [S, L, H]
    const float* __restrict__ ihw, const float* __restrict__ ihb,
    const float* __restrict__ hhb,
    const float* __restrict__ dW1w, const float* __restrict__ dW1b,
    const float* __restrict__ dW2w, const float* __restrict__ dW2b,
    const float* __restrict__ dVw,  const float* __restrict__ dVb,
    const float* __restrict__ predw, const float* __restrict__ predb,
    float* __restrict__ out)           // [S]
{
  int s = blockIdx.x;
  int g = threadIdx.x;
  int j = g & 63;
  int q = g >> 6;

  __shared__ float dv_s[NL][NH];
  __shared__ float gl[NL][NG];
  __shared__ float hd[NL][NH];

  for (int i = g; i < NL * NH; i += 256)
    ((float*)dv_s)[i] = day_vec[(size_t)s * NL * NH + i];
  __syncthreads();

  float ihcol[NH];
#pragma unroll
  for (int k = 0; k < NH; ++k)
    ihcol[k] = ihw[((size_t)s * NH + k) * NG + g];
  float bias = ihb[(size_t)s * NG + g] + hhb[(size_t)s * NG + g];

  bool is_gpart = (g >= 128 && g < 192);
  for (int l = 0; l < NL; ++l) {
    float acc = bias;
#pragma unroll
    for (int k = 0; k < NH; ++k) acc = fmaf(dv_s[l][k], ihcol[k], acc);
    gl[l][g] = is_gpart ? ftanh(acc) : fsigmoid(acc);
  }
  __syncthreads();
  for (int l = q; l < NL; l += 4) {
    float cd = gl[l][j] * gl[l][128 + j];       // sig(i)*tanh(g)
    hd[l][j] = gl[l][192 + j] * ftanh(cd);      // sig(o)*tanh(c)
  }
  __syncthreads();

  if (g < 64) {
    int k = g;
    float dw1c[NH], dw2c[NH];
#pragma unroll
    for (int h = 0; h < NH; ++h) {
      dw1c[h] = dW1w[((size_t)s * NH + h) * NH + k];
      dw2c[h] = dW2w[((size_t)s * NH + h) * NH + k];
    }
    float b1 = dW1b[(size_t)s * NH + k];
    float b2 = dW2b[(size_t)s * NH + k];
    float dv = dVw[(size_t)s * NH + k];
    float dvb = dVb[s];

    float sc[NL];
#pragma unroll
    for (int l = 0; l < NL; ++l) {
      float x1 = b1, x2 = b2;
#pragma unroll
      for (int h = 0; h < NH; ++h) {
        x1 = fmaf(hd[l][h], dw1c[h], x1);
        x2 = fmaf(hd[l][h], dw2c[h], x2);
      }
      float v = ftanh(x1 + x2) * dv;
#pragma unroll
      for (int off = 32; off >= 1; off >>= 1) v += __shfl_xor(v, off);
      sc[l] = v + dvb;
    }
    float mx = sc[0];
#pragma unroll
    for (int l = 1; l < NL; ++l) mx = fmaxf(mx, sc[l]);
    float sum = 0.f;
#pragma unroll
    for (int l = 0; l < NL; ++l) { sc[l] = __expf(sc[l] - mx); sum += sc[l]; }
    float inv = __builtin_amdgcn_rcpf(sum);
    float sv = 0.f;
#pragma unroll
    for (int l = 0; l < NL; ++l) sv = fmaf(sc[l] * inv, hd[l][k], sv);

    float p = sv * predw[k];
#pragma unroll
    for (int off = 32; off >= 1; off >>= 1) p += __shfl_xor(p, off);
    if (k == 0) {
      float x = p + predb[0];
      out[s] = (x >= 0.f) ? x : 0.01f * x;
    }
  }
}

// ---------------------------------------------------------------------------
extern "C" void kernel_launch(void* const* d_in, const int* in_sizes, int n_in,
                              void* d_out, int out_size, void* d_ws, size_t ws_size,
                              hipStream_t stream) {
  (void)in_sizes; (void)n_in; (void)out_size; (void)ws_size;

  const float* text    = (const float*)d_in[0];
  const float* time_in = (const float*)d_in[1];
  const float* Wdw     = (const float*)d_in[2];
  const float* Wdb     = (const float*)d_in[3];
  const float* Wallw   = (const float*)d_in[4];
  const float* Wallb   = (const float*)d_in[5];
  const float* Uallw   = (const float*)d_in[6];
  const float* Uallb   = (const float*)d_in[7];
  const float* tW1w    = (const float*)d_in[8];
  const float* tW1b    = (const float*)d_in[9];
  const float* tW2w    = (const float*)d_in[10];
  const float* tW2b    = (const float*)d_in[11];
  const float* tVw     = (const float*)d_in[12];
  const float* tVb     = (const float*)d_in[13];
  const float* ihw     = (const float*)d_in[14];
  const float* ihb     = (const float*)d_in[15];
  const float* hhb     = (const float*)d_in[16];
  const float* dW1w    = (const float*)d_in[17];
  const float* dW1b    = (const float*)d_in[18];
  const float* dW2w    = (const float*)d_in[19];
  const float* dW2b    = (const float*)d_in[20];
  const float* dVw     = (const float*)d_in[21];
  const float* dVb     = (const float*)d_in[22];
  const float* predw   = (const float*)d_in[23];
  const float* predb   = (const float*)d_in[24];

  float* ws      = (float*)d_ws;
  float* u       = ws;                                // S*300*256 f32
  float* day_vec = u + (size_t)NS * NM * NG;          // S*L*H    f32
  half_t* Bf16   = (half_t*)(day_vec + (size_t)NS * NL * NH); // S*256*768 f16

  convB_kernel<<<NS * 192, 256, 0, stream>>>(Uallw, Bf16);
  gemm_mfma_kernel<<<NS * 10, 256, 0, stream>>>(text, Bf16, Uallb, u);
  lstm_attn_kernel<<<NS * NL, 64, 0, stream>>>(u, time_in, Wdw, Wdb,
                                               Wallw, Wallb,
                                               tW1w, tW1b, tW2w, tW2b,
                                               tVw, tVb, day_vec);
  day_head_kernel<<<NS, 256, 0, stream>>>(day_vec, ihw, ihb, hhb,
                                          dW1w, dW1b, dW2w, dW2b, dVw, dVb,
                                          predw, predb, (float*)d_out);
}